// Round 12
// baseline (232.085 us; speedup 1.0000x reference)
//
#include <hip/hip_runtime.h>
#include <hip/hip_bf16.h>

// SrnmSpmm: out[b,s,n] = sum_k x[b,s,keep[k]] * values[n,k] + bias[n]
// keep: cols {8i, 8i+2} of D_IN=4096 -> K=1024. M = B*S = 16384, N = 4096.
//
// R12: 4 waves x 128x128 wave-tile (256^2 block, 256 thr, 1 wave/SIMD,
// unified-VGPR acc): LDS-port read traffic 192->128 b128/K-tile (A amp 4->2).
// 2 phases/K-tile {vm(16); BAR; reads; stage-pair; BAR; MFMA32}, 8x16KiB
// ring, exact counted vmcnt, 4-phase prefetch lead. Plain C stores (NT
// scalar stores inflate WRITE_SIZE). 32x32x16 MFMA (mappings verified R11).

#define M_TOTAL 16384
#define DIN     4096
#define KDIM    1024
#define NDIM    4096

typedef unsigned short u16;
typedef unsigned int   u32;
typedef __bf16 bf16x8 __attribute__((ext_vector_type(8)));
typedef float  f32x4  __attribute__((ext_vector_type(4)));
typedef float  f32x16 __attribute__((ext_vector_type(16)));

typedef const void __attribute__((address_space(1)))* gp_t;
typedef void __attribute__((address_space(3)))*       lp_t;

__device__ __forceinline__ u16 f2bf(float f) {
    u32 u = __float_as_uint(f);
    u += 0x7FFFu + ((u >> 16) & 1u);   // round-to-nearest-even
    return (u16)(u >> 16);
}
__device__ __forceinline__ u32 pack2(float a, float b) {
    return (u32)f2bf(a) | ((u32)f2bf(b) << 16);
}

// Pass 1 (unchanged): compact x / cast values, NT loads, coalesced writes.
__global__ void prep_kernel(const float* __restrict__ x, uint2* __restrict__ xg2,
                            const float* __restrict__ vals, uint4* __restrict__ vb4) {
    const int tid = threadIdx.x;
    if (blockIdx.x < 4096) {
        int i = blockIdx.x * 256 + tid;
        const int stride = 4096 * 256;
#pragma unroll
        for (int it = 0; it < 4; ++it, i += stride) {
            const f32x4* p = (const f32x4*)(x + (size_t)i * 16);
            f32x4 f0 = __builtin_nontemporal_load(p);
            f32x4 f1 = __builtin_nontemporal_load(p + 2);
            xg2[i] = make_uint2(pack2(f0.x, f0.z), pack2(f1.x, f1.z));
        }
    } else {
        const int i = (blockIdx.x - 4096) * 256 + tid;
        const f32x4* p = (const f32x4*)(vals + (size_t)i * 8);
        f32x4 a = __builtin_nontemporal_load(p);
        f32x4 b = __builtin_nontemporal_load(p + 1);
        vb4[i] = make_uint4(pack2(a.x, a.y), pack2(a.z, a.w),
                            pack2(b.x, b.y), pack2(b.z, b.w));
    }
}

// ---------------- 256x256 GEMM: 4 waves x 128x128, 32x32x16 MFMA -----------
// Slot (tile tt, kh) = A[256r][32k] 16KiB @ (d*2+kh)*16K (d=tt&1) and
// B[256c][32k] 16KiB @ 64K + (d*2+kh)*16K; staged together: 8 gload_lds of
// 4 KiB (256 thr x 16B), dest linear, source pre-swizzled (st_16x32 + bit4,
// as verified in R11). Subtile [16r][32c]=1KiB; read addr = region +
// subtile*1024 + fl_base + (((ks<<5)+acol)^aswz).
// Phase(u,kh) = { VM; BAR; LOADA+LOADB (16 b128); STAGE(pair); BAR; MFMA32 }.
// Stage schedule: ph(u,0) stages (u+1,kh1); ph(u,1) stages (u+2,kh0).
//   -> landing lead 4 phases; overwrite always >=1 barrier after last read.
// vmcnt: steady VM(16) (= 2 newest 8-gload pairs outstanding, exact);
// first 3 phases after an epilogue VM(63) (C-stores are newer than needed).

#define LOADA(d, kh) { _Pragma("unroll") \
    for (int mf = 0; mf < 4; ++mf) { _Pragma("unroll") \
    for (int ks = 0; ks < 2; ++ks) \
        af[mf * 2 + ks] = *(const bf16x8*)(lds + ((d) * 2 + (kh)) * 16384 \
            + (wr2 * 8 + 2 * mf) * 1024 + fl_base + (((ks << 5) + acol) ^ aswz)); } }

#define LOADB(d, kh) { _Pragma("unroll") \
    for (int nf = 0; nf < 4; ++nf) { _Pragma("unroll") \
    for (int ks = 0; ks < 2; ++ks) \
        bfr[nf * 2 + ks] = *(const bf16x8*)(lds + 65536 + ((d) * 2 + (kh)) * 16384 \
            + (wc2 * 8 + 2 * nf) * 1024 + fl_base + (((ks << 5) + acol) ^ aswz)); } }

#define MFMA32() { \
    __builtin_amdgcn_s_setprio(1); \
    _Pragma("unroll") for (int ks = 0; ks < 2; ++ks) \
    _Pragma("unroll") for (int mf = 0; mf < 4; ++mf) \
    _Pragma("unroll") for (int nf = 0; nf < 4; ++nf) \
        acc[mf][nf] = __builtin_amdgcn_mfma_f32_32x32x16_bf16( \
            af[mf * 2 + ks], bfr[nf * 2 + ks], acc[mf][nf], 0, 0, 0); \
    __builtin_amdgcn_s_setprio(0); }

#define BAR()  __builtin_amdgcn_s_barrier()
#define VM16() asm volatile("s_waitcnt vmcnt(16)" ::: "memory")
#define VM63() asm volatile("s_waitcnt vmcnt(63)" ::: "memory")

// Phase: W; BAR (all waves' needed stages landed); reads; stage; BAR; MFMA.
#define PH(W, d, kh, STG) { W; BAR(); LOADA(d, kh); LOADB(d, kh); STG; BAR(); MFMA32(); }

__global__ __launch_bounds__(256, 1) void gemm_kernel(
    const u16* __restrict__ A, const u16* __restrict__ Bv,
    const float* __restrict__ bias, float* __restrict__ C)
{
    __shared__ __align__(1024) char lds[131072];

    const int tid  = threadIdx.x;
    const int lane = tid & 63;
    const int wid  = tid >> 6;      // 0..3
    const int wr2  = wid >> 1;      // 0..1 (M half)
    const int wc2  = wid & 1;       // 0..1 (N half)

    // Persistent mapping (R5b): XCD (bb&7) slab; btn fixed; 4 rounds btm0+2r.
    const int bb   = blockIdx.x;
    const int btm0 = (bb & 7) * 8 + (bb >> 7);
    const int btn  = (bb >> 3) & 15;

    // Staging source (pre-swizzled global addr; LDS dest linear).
    // thread t: row t>>2 (+64j per gload), 16B at col (t&3)*8; swizzle bits:
    // byte5 ^= row-bit3 (t-bit5), byte4 ^= row-bit4 (t-bit6).
    const int st_r0 = tid >> 2;
    const int st_ck = ((tid & 3) * 8) ^ ((tid & 32) >> 1) ^ ((tid & 64) >> 3);
    const u16* A0  = A  + (size_t)(btm0 * 256 + st_r0) * KDIM + st_ck;
    const u16* Bs0 = Bv + (size_t)(btn  * 256 + st_r0) * KDIM + st_ck;
    const int dst0 = tid * 16;

    // Fragment read constants (verified R11).
    const int fl_base = (lane & 15) * 64 + ((lane >> 4) & 1) * 1024;
    const int aswz    = (((lane >> 3) & 1) << 5) ^ (((lane >> 4) & 1) << 4);
    const int acol    = ((lane >> 5) & 1) * 16;

    // Stage pair (tile tt, kh): 4 A-gloads + 4 B-gloads (4 KiB each).
    auto STAGE = [&](const u16* asrc, int tt, int kh) {
        const int d  = tt & 1;
        const int ko = (tt & 15) * 64 + kh * 32;
        const int ab = (d * 2 + kh) * 16384;
#pragma unroll
        for (int j = 0; j < 4; ++j)
            __builtin_amdgcn_global_load_lds((gp_t)(asrc + (size_t)(64 * j) * KDIM + ko),
                (lp_t)(lds + ab + j * 4096 + dst0), 16, 0, 0);
#pragma unroll
        for (int j = 0; j < 4; ++j)
            __builtin_amdgcn_global_load_lds((gp_t)(Bs0 + (size_t)(64 * j) * KDIM + ko),
                (lp_t)(lds + 65536 + ab + j * 4096 + dst0), 16, 0, 0);
    };

    // bias (btn fixed): cols wc2*128 + nf*32 + (lane&31).
    const int c_colb = btn * 256 + wc2 * 128 + (lane & 31);
    float bvr[4];
#pragma unroll
    for (int n = 0; n < 4; ++n) bvr[n] = bias[c_colb + n * 32];

    f32x16 acc[4][4] = {};
    bf16x8 af[8], bfr[8];

    // Prologue: pairs (0,kh0), (0,kh1), (1,kh0) — 24 gloads in flight.
    STAGE(A0, 0, 0); STAGE(A0, 0, 1); STAGE(A0, 1, 0);

#pragma unroll 1
    for (int r = 0; r < 4; ++r) {
        const u16* Ar = A0 + (size_t)r * 512 * KDIM;
        const u16* An = (r < 3) ? (Ar + 512 * KDIM) : Ar;  // r=3: dummy re-stage

        // K-tile pair (0,1): post-epilogue rounds use VM63 for 3 phases
        // (needed stages predate the 256 C-stores; 63 newer ops guarantee).
        if (r == 0) {
            PH(VM16(), 0, 0, STAGE(Ar, 1, 1));
            PH(VM16(), 0, 1, STAGE(Ar, 2, 0));
            PH(VM16(), 1, 0, STAGE(Ar, 2, 1));
            PH(VM16(), 1, 1, STAGE(Ar, 3, 0));
        } else {
            PH(VM63(), 0, 0, STAGE(Ar, 1, 1));
            PH(VM63(), 0, 1, STAGE(Ar, 2, 0));
            PH(VM63(), 1, 0, STAGE(Ar, 2, 1));
            PH(VM16(), 1, 1, STAGE(Ar, 3, 0));
        }

#pragma unroll 1
        for (int tt = 2; tt < 16; tt += 2) {
            const u16* s1 = Ar;                         // tt+1 <= 15
            const u16* s2 = (tt + 2 < 16) ? Ar : An;
            const u16* s3 = (tt + 3 < 16) ? Ar : An;
            PH(VM16(), 0, 0, STAGE(s1, tt + 1, 1));
            PH(VM16(), 0, 1, STAGE(s2, tt + 2, 0));
            PH(VM16(), 1, 0, STAGE(s2, tt + 2, 1));
            PH(VM16(), 1, 1, STAGE(s3, tt + 3, 0));
        }

        // Epilogue round r: plain coalesced stores (col = lane&31, 128B segs).
        // C/D (32x32): col = lane&31, row = (reg&3) + 8*(reg>>2) + 4*(lane>>5).
        const int c_row0 = (btm0 + 2 * r) * 256 + wr2 * 128 + ((lane >> 5) & 1) * 4;
#pragma unroll
        for (int mf = 0; mf < 4; ++mf) {
#pragma unroll
            for (int nf = 0; nf < 4; ++nf) {
                f32x16 a = acc[mf][nf];
#pragma unroll
                for (int q = 0; q < 4; ++q) {
#pragma unroll
                    for (int rr = 0; rr < 4; ++rr) {
                        const int row = c_row0 + mf * 32 + q * 8 + rr;
                        C[(size_t)row * NDIM + c_colb + nf * 32] = a[q * 4 + rr] + bvr[nf];
                    }
                }
#pragma unroll
                for (int z = 0; z < 16; ++z) acc[mf][nf][z] = 0.f;
            }
        }
    }
}

extern "C" void kernel_launch(void* const* d_in, const int* in_sizes, int n_in,
                              void* d_out, int out_size, void* d_ws, size_t ws_size,
                              hipStream_t stream) {
    const float* x      = (const float*)d_in[0];
    const float* values = (const float*)d_in[1];
    const float* bias   = (const float*)d_in[2];
    float* out = (float*)d_out;

    // ws: xg bf16 [16384][1024] = 32 MB @ 0; values bf16 [4096][1024] @ 32 MB
    u16* xg = (u16*)d_ws;
    u16* vb = (u16*)((char*)d_ws + ((size_t)32 << 20));

    prep_kernel<<<6144, 256, 0, stream>>>(x, (uint2*)xg, values, (uint4*)vb);
    gemm_kernel<<<256, 256, 0, stream>>>(xg, vb, bias, out);
}